// Round 8
// baseline (221.324 us; speedup 1.0000x reference)
//
#include <hip/hip_runtime.h>
#include <stdint.h>

#define N_NODES 50000
#define N_EDGES 800000
#define CAP 80   // bucket capacity; deg ~ Poisson(16), P(deg>80) ~ 1e-25
// D_IN=128, H1=128, H2=64, C=2 — inputs fp32; intermediates bf16

typedef __attribute__((ext_vector_type(8))) short short8;     // 8 bf16 (4 VGPRs)
typedef __attribute__((ext_vector_type(4))) float floatx4;    // MFMA acc

// ---------- bf16 helpers ----------
__device__ __forceinline__ float bflo(uint32_t u) { return __uint_as_float(u << 16); }
__device__ __forceinline__ float bfhi(uint32_t u) { return __uint_as_float(u & 0xffff0000u); }
__device__ __forceinline__ unsigned short f2b(float f) {
    uint32_t u = __float_as_uint(f);
    u += 0x7fffu + ((u >> 16) & 1u);   // RNE
    return (unsigned short)(u >> 16);
}

// ---------- 1. prep: zero cursor, build Wt1/Wt2 bf16 transposes ----------
__global__ void k_prep(const float* __restrict__ W1, const float* __restrict__ W2,
                       unsigned short* __restrict__ Wt1, unsigned short* __restrict__ Wt2,
                       int* __restrict__ cursor) {
    int gid = blockIdx.x * 256 + threadIdx.x;
    if (gid < 16384) {                     // Wt1[n][k] = bf16(W1[k][n])
        int k = gid >> 7, n = gid & 127;
        Wt1[n * 128 + k] = f2b(W1[gid]);
    } else if (gid < 24576) {              // Wt2[n][k] = bf16(W2[k][n])
        int j = gid - 16384;
        int k = j >> 6, n = j & 63;
        Wt2[n * 128 + k] = f2b(W2[j]);
    } else if (gid < 24576 + N_NODES) {
        cursor[gid - 24576] = 0;
    }
}

// ---------- 2. merged: bucket-append scatter (blocks 0..3124) || MFMA GEMM1 ----------
// scatter: r = atomicAdd(cursor[d]); csr[d*CAP+r] = s  (ONE edge pass: CSR + degrees)
// gemm1:   h1b[v] = bf16(x[v] @ W1)   (unscaled — dinv applied per-edge in agg1)
__global__ __launch_bounds__(256) void k_scat_g1(const int* __restrict__ src,
                                                 const int* __restrict__ dst,
                                                 int* __restrict__ cursor,
                                                 int* __restrict__ csr,
                                                 const float* __restrict__ x,
                                                 const unsigned short* __restrict__ Wt1,
                                                 unsigned short* __restrict__ h1b) {
    __shared__ unsigned short At[64 * 136];   // 17.0 KB (pad 8 bf16)
    __shared__ unsigned short Bt[128 * 136];  // 34.0 KB
    if (blockIdx.x < 3125) {                  // ---- scatter branch ----
        int e = blockIdx.x * 256 + threadIdx.x;
        int s = src[e], d = dst[e];
        if ((unsigned)s >= N_NODES || (unsigned)d >= N_NODES) return;
        int r = atomicAdd(&cursor[d], 1);
        if (r < CAP) csr[d * CAP + r] = s;
        return;
    }
    // ---- gemm1 branch ----
    int t = threadIdx.x;
    int row0 = (blockIdx.x - 3125) * 64;
    for (int i = t; i < 2048; i += 256) {     // stage Bt (Wt1 [n][k] bf16)
        int n = i >> 4, kc = (i & 15) * 8;
        *(uint4*)&Bt[n * 136 + kc] = *(const uint4*)(Wt1 + n * 128 + kc);
    }
    for (int i = t; i < 1024; i += 256) {     // stage At: fp32 -> bf16
        int r = i >> 4, kc = (i & 15) * 8;
        int g = row0 + r; if (g >= N_NODES) g = N_NODES - 1;
        const float* p = x + g * 128 + kc;
        float4 a = *(const float4*)p, b = *(const float4*)(p + 4);
        uint4 o;
        o.x = (uint32_t)f2b(a.x) | ((uint32_t)f2b(a.y) << 16);
        o.y = (uint32_t)f2b(a.z) | ((uint32_t)f2b(a.w) << 16);
        o.z = (uint32_t)f2b(b.x) | ((uint32_t)f2b(b.y) << 16);
        o.w = (uint32_t)f2b(b.z) | ((uint32_t)f2b(b.w) << 16);
        *(uint4*)&At[r * 136 + kc] = o;
    }
    __syncthreads();
    int wv = t >> 6, lane = t & 63;
    int m = lane & 15, qd = lane >> 4;
    floatx4 acc[8];
    #pragma unroll
    for (int c = 0; c < 8; c++) acc[c] = (floatx4){0.f, 0.f, 0.f, 0.f};
    const unsigned short* ap = &At[(wv * 16 + m) * 136 + qd * 8];
    const unsigned short* bp = &Bt[m * 136 + qd * 8];
    #pragma unroll
    for (int kk = 0; kk < 4; kk++) {
        short8 af = *(const short8*)(ap + kk * 32);
        #pragma unroll
        for (int c = 0; c < 8; c++) {
            short8 bf = *(const short8*)(bp + c * 16 * 136 + kk * 32);
            acc[c] = __builtin_amdgcn_mfma_f32_16x16x32_bf16(af, bf, acc[c], 0, 0, 0);
        }
    }
    #pragma unroll
    for (int reg = 0; reg < 4; reg++) {       // D[row=qd*4+reg][col=16c+m]
        int g = row0 + wv * 16 + qd * 4 + reg;
        if (g < N_NODES) {
            #pragma unroll
            for (int c = 0; c < 8; c++)
                h1b[g * 128 + c * 16 + m] = f2b(acc[c][reg]);
        }
    }
}

// ---------- 3. fused agg1 + GEMM2 ----------
// agg: r1[v] = relu(dinv[v]*(Σ dinv[s]*h1b[s] + dinv[v]*h1b[v]) + b1) -> LDS A-tile
// gemm: h2s[v] = dinv[v] * (r1 @ W2) via 1 MFMA col-tile per wave.
__global__ __launch_bounds__(256) void k_agg1g2(const unsigned short* __restrict__ h1b,
                                                const unsigned short* __restrict__ Wt2,
                                                const int* __restrict__ csr,
                                                const int* __restrict__ cursor,
                                                const float* __restrict__ b1,
                                                unsigned short* __restrict__ h2s) {
    __shared__ unsigned short Bt[64 * 136];   // Wt2 [n=64][k=128] staged
    __shared__ unsigned short At[16 * 136];   // r1 tile [16 rows][128 k]
    int t = threadIdx.x;
    for (int i = t; i < 1024; i += 256) {     // stage Bt2
        int n = i >> 4, kc = (i & 15) * 8;
        *(uint4*)&Bt[n * 136 + kc] = *(const uint4*)(Wt2 + n * 128 + kc);
    }
    int wv = t >> 6, lane = t & 63;
    int q = lane >> 4, l = lane & 15;
    int v0 = blockIdx.x * 16;
    int v = v0 + wv * 4 + q;
    int vv = (v < N_NODES) ? v : N_NODES - 1;
    int n = (v < N_NODES) ? cursor[vv] : 0;
    float dv = rsqrtf((float)n + 1.0f);
    int n_eff = min(n, CAP);
    const int* cs = csr + vv * CAP;
    int nmax = n_eff;
    nmax = max(nmax, __shfl_xor(nmax, 16));
    nmax = max(nmax, __shfl_xor(nmax, 32));
    float a0, a1, a2, a3, a4, a5, a6, a7;
    {   // self-loop row: dv * h1b[v]
        uint4 p = *(const uint4*)(h1b + vv * 128 + l * 8);
        a0 = dv * bflo(p.x); a1 = dv * bfhi(p.x); a2 = dv * bflo(p.y); a3 = dv * bfhi(p.y);
        a4 = dv * bflo(p.z); a5 = dv * bfhi(p.z); a6 = dv * bflo(p.w); a7 = dv * bfhi(p.w);
    }
    for (int base = 0; base < nmax; base += 16) {
        int idx = base + l;
        int e = (idx < n_eff) ? cs[idx] : 0;  // coalesced per quarter
        int mm = nmax - base; if (mm > 16) mm = 16;
        #pragma unroll 4
        for (int i = 0; i < mm; i++) {
            int s = __shfl(e, (q << 4) + i);
            if (base + i < n_eff) {           // uniform within quarter
                float ds = rsqrtf((float)cursor[s] + 1.0f);  // 200KB table, L2-hit
                uint4 p = *(const uint4*)(h1b + s * 128 + l * 8);
                a0 = fmaf(ds, bflo(p.x), a0); a1 = fmaf(ds, bfhi(p.x), a1);
                a2 = fmaf(ds, bflo(p.y), a2); a3 = fmaf(ds, bfhi(p.y), a3);
                a4 = fmaf(ds, bflo(p.z), a4); a5 = fmaf(ds, bfhi(p.z), a5);
                a6 = fmaf(ds, bflo(p.w), a6); a7 = fmaf(ds, bfhi(p.w), a7);
            }
        }
    }
    {
        float4 bL = *(const float4*)(b1 + l * 8);
        float4 bH = *(const float4*)(b1 + l * 8 + 4);
        a0 = fmaxf(fmaf(dv, a0, bL.x), 0.f); a1 = fmaxf(fmaf(dv, a1, bL.y), 0.f);
        a2 = fmaxf(fmaf(dv, a2, bL.z), 0.f); a3 = fmaxf(fmaf(dv, a3, bL.w), 0.f);
        a4 = fmaxf(fmaf(dv, a4, bH.x), 0.f); a5 = fmaxf(fmaf(dv, a5, bH.y), 0.f);
        a6 = fmaxf(fmaf(dv, a6, bH.z), 0.f); a7 = fmaxf(fmaf(dv, a7, bH.w), 0.f);
        uint4 o;
        o.x = (uint32_t)f2b(a0) | ((uint32_t)f2b(a1) << 16);
        o.y = (uint32_t)f2b(a2) | ((uint32_t)f2b(a3) << 16);
        o.z = (uint32_t)f2b(a4) | ((uint32_t)f2b(a5) << 16);
        o.w = (uint32_t)f2b(a6) | ((uint32_t)f2b(a7) << 16);
        *(uint4*)&At[(wv * 4 + q) * 136 + l * 8] = o;   // r1 tile row
    }
    __syncthreads();
    // MFMA: wave wv -> col-tile wv (cols 16wv..16wv+15)
    int m = lane & 15, qd = lane >> 4;
    floatx4 acc = (floatx4){0.f, 0.f, 0.f, 0.f};
    const unsigned short* ap = &At[m * 136 + qd * 8];
    const unsigned short* bp = &Bt[(wv * 16 + m) * 136 + qd * 8];
    #pragma unroll
    for (int kk = 0; kk < 4; kk++) {
        short8 af = *(const short8*)(ap + kk * 32);
        short8 bf = *(const short8*)(bp + kk * 32);
        acc = __builtin_amdgcn_mfma_f32_16x16x32_bf16(af, bf, acc, 0, 0, 0);
    }
    #pragma unroll
    for (int reg = 0; reg < 4; reg++) {
        int g = v0 + qd * 4 + reg;
        if (g < N_NODES) {
            float dg = rsqrtf((float)cursor[g] + 1.0f);   // prescale h2 rows
            h2s[g * 64 + wv * 16 + m] = f2b(dg * acc[reg]);
        }
    }
}

// ---------- 4. agg2 + head: h3 = relu(dv*Σ h2s + b2); out = log_softmax(h3@Wo+bo)
__global__ __launch_bounds__(256) void k_agg2(const unsigned short* __restrict__ h2s,
                                              const int* __restrict__ csr,
                                              const int* __restrict__ cursor,
                                              const float* __restrict__ b2,
                                              const float* __restrict__ Wo,
                                              const float* __restrict__ bo,
                                              float* __restrict__ out) {
    int wave = (blockIdx.x * 256 + threadIdx.x) >> 6;
    int lane = threadIdx.x & 63;
    int q = lane >> 4, l = lane & 15;
    int v = wave * 4 + q;
    bool valid = v < N_NODES;
    int vv = valid ? v : N_NODES - 1;
    int n = valid ? cursor[vv] : 0;
    float dv = rsqrtf((float)n + 1.0f);
    int n_eff = min(n, CAP);
    const int* cs = csr + vv * CAP;
    int nmax = n_eff;
    nmax = max(nmax, __shfl_xor(nmax, 16));
    nmax = max(nmax, __shfl_xor(nmax, 32));
    float a0, a1, a2, a3;
    {   // self-loop: h2s already prescaled by dinv
        uint2 p = *(const uint2*)(h2s + vv * 64 + l * 4);
        a0 = bflo(p.x); a1 = bfhi(p.x); a2 = bflo(p.y); a3 = bfhi(p.y);
    }
    for (int base = 0; base < nmax; base += 16) {
        int idx = base + l;
        int e = (idx < n_eff) ? cs[idx] : 0;
        int mm = nmax - base; if (mm > 16) mm = 16;
        #pragma unroll 4
        for (int i = 0; i < mm; i++) {
            int s = __shfl(e, (q << 4) + i);
            if (base + i < n_eff) {
                uint2 p = *(const uint2*)(h2s + s * 64 + l * 4);
                a0 += bflo(p.x); a1 += bfhi(p.x); a2 += bflo(p.y); a3 += bfhi(p.y);
            }
        }
    }
    float4 bb = *(const float4*)(b2 + l * 4);
    a0 = fmaxf(fmaf(dv, a0, bb.x), 0.f);
    a1 = fmaxf(fmaf(dv, a1, bb.y), 0.f);
    a2 = fmaxf(fmaf(dv, a2, bb.z), 0.f);
    a3 = fmaxf(fmaf(dv, a3, bb.w), 0.f);
    float4 w01 = *(const float4*)(Wo + l * 8);
    float4 w23 = *(const float4*)(Wo + l * 8 + 4);
    float l0 = a0 * w01.x + a1 * w01.z + a2 * w23.x + a3 * w23.z;
    float l1 = a0 * w01.y + a1 * w01.w + a2 * w23.y + a3 * w23.w;
    #pragma unroll
    for (int off = 8; off > 0; off >>= 1) {
        l0 += __shfl_xor(l0, off);
        l1 += __shfl_xor(l1, off);
    }
    if (l == 0 && valid) {
        float2 bof = *(const float2*)bo;
        l0 += bof.x; l1 += bof.y;
        float m = fmaxf(l0, l1);
        float ls = m + __logf(__expf(l0 - m) + __expf(l1 - m));
        *(float2*)(out + v * 2) = make_float2(l0 - ls, l1 - ls);
    }
}

extern "C" void kernel_launch(void* const* d_in, const int* in_sizes, int n_in,
                              void* d_out, int out_size, void* d_ws, size_t ws_size,
                              hipStream_t stream) {
    const float* x  = (const float*)d_in[0];
    const int* ei   = (const int*)d_in[1];
    const float* W1 = (const float*)d_in[2];
    const float* b1 = (const float*)d_in[3];
    const float* W2 = (const float*)d_in[4];
    const float* b2 = (const float*)d_in[5];
    const float* Wo = (const float*)d_in[6];
    const float* bo = (const float*)d_in[7];
    float* out      = (float*)d_out;
    const int* src = ei;             // edge_index[0]
    const int* dst = ei + N_EDGES;   // edge_index[1]

    char* w = (char*)d_ws;
    int* cursor = (int*)(w + 0);                           // 200 KB (degrees after scatter)
    int* csr    = (int*)(w + 200704);                      // 16 MB  [node][CAP]
    unsigned short* Wt1 = (unsigned short*)(w + 16200704); // 32 KB  [n=128][k=128]
    unsigned short* Wt2 = (unsigned short*)(w + 16233472); // 16 KB  [n=64][k=128]
    unsigned short* h1b = (unsigned short*)(w + 16249856); // 12.8 MB (unscaled)
    unsigned short* h2s = (unsigned short*)(w + 29049856); // 6.4 MB  (dinv-prescaled)
    // total ws usage: ~35.4 MB

    k_prep   <<<292, 256, 0, stream>>>(W1, W2, Wt1, Wt2, cursor);
    k_scat_g1<<<3907, 256, 0, stream>>>(src, dst, cursor, csr, x, Wt1, h1b);
    k_agg1g2 <<<3125, 256, 0, stream>>>(h1b, Wt2, csr, cursor, b1, h2s);
    k_agg2   <<<3125, 256, 0, stream>>>(h2s, csr, cursor, b2, Wo, bo, out);
}

// Round 9
// 210.382 us; speedup vs baseline: 1.0520x; 1.0520x over previous
//
#include <hip/hip_runtime.h>
#include <stdint.h>

#define N_NODES 50000
#define N_EDGES 800000
#define CAP 80   // bucket capacity; deg ~ Poisson(16), P(deg>80) ~ 1e-25
// D_IN=128, H1=128, H2=64, C=2 — inputs fp32; intermediates bf16 (dinv-prescaled)

typedef __attribute__((ext_vector_type(8))) short short8;     // 8 bf16 (4 VGPRs)
typedef __attribute__((ext_vector_type(4))) float floatx4;    // MFMA acc

// ---------- bf16 helpers ----------
__device__ __forceinline__ float bflo(uint32_t u) { return __uint_as_float(u << 16); }
__device__ __forceinline__ float bfhi(uint32_t u) { return __uint_as_float(u & 0xffff0000u); }
__device__ __forceinline__ unsigned short f2b(float f) {
    uint32_t u = __float_as_uint(f);
    u += 0x7fffu + ((u >> 16) & 1u);   // RNE
    return (unsigned short)(u >> 16);
}

// ---------- 1. prep: zero counts, build Wt1/Wt2 bf16 transposes ----------
__global__ void k_prep(const float* __restrict__ W1, const float* __restrict__ W2,
                       unsigned short* __restrict__ Wt1, unsigned short* __restrict__ Wt2,
                       int* __restrict__ counts) {
    int gid = blockIdx.x * 256 + threadIdx.x;
    if (gid < 16384) {                     // Wt1[n][k] = bf16(W1[k][n])
        int k = gid >> 7, n = gid & 127;
        Wt1[n * 128 + k] = f2b(W1[gid]);
    } else if (gid < 24576) {              // Wt2[n][k] = bf16(W2[k][n])
        int j = gid - 16384;
        int k = j >> 6, n = j & 63;
        Wt2[n * 128 + k] = f2b(W2[j]);
    } else if (gid < 24576 + N_NODES) {
        counts[gid - 24576] = 0;
    }
}

// ---------- 2. one-pass CSR: count + bucket-append. ZERO LDS -> full occupancy ----------
__global__ __launch_bounds__(256) void k_scat(const int* __restrict__ src,
                                              const int* __restrict__ dst,
                                              int* __restrict__ counts,
                                              int* __restrict__ csr) {
    int e = blockIdx.x * 256 + threadIdx.x;   // 3125*256 == N_EDGES exactly
    int s = src[e], d = dst[e];
    if ((unsigned)s >= N_NODES || (unsigned)d >= N_NODES) return;
    int r = atomicAdd(&counts[d], 1);
    if (r < CAP) csr[d * CAP + r] = s;
}

// ---------- 3. MFMA GEMM1: h1s[v] = dinv[v] * (bf16(x[v]) @ bf16(W1)) ----------
// 64 rows/block, full K=128 in LDS. dinv computed from counts (final after k_scat).
__global__ __launch_bounds__(256) void k_gemm1(const float* __restrict__ x,
                                               const unsigned short* __restrict__ Wt1,
                                               const int* __restrict__ counts,
                                               unsigned short* __restrict__ h1s) {
    __shared__ unsigned short At[64 * 136];   // 17.0 KB (pad 8 bf16)
    __shared__ unsigned short Bt[128 * 136];  // 34.0 KB
    int t = threadIdx.x;
    int row0 = blockIdx.x * 64;
    for (int i = t; i < 2048; i += 256) {     // stage Bt (Wt1 [n][k] bf16)
        int n = i >> 4, kc = (i & 15) * 8;
        *(uint4*)&Bt[n * 136 + kc] = *(const uint4*)(Wt1 + n * 128 + kc);
    }
    for (int i = t; i < 1024; i += 256) {     // stage At: fp32 -> bf16
        int r = i >> 4, kc = (i & 15) * 8;
        int g = row0 + r; if (g >= N_NODES) g = N_NODES - 1;
        const float* p = x + g * 128 + kc;
        float4 a = *(const float4*)p, b = *(const float4*)(p + 4);
        uint4 o;
        o.x = (uint32_t)f2b(a.x) | ((uint32_t)f2b(a.y) << 16);
        o.y = (uint32_t)f2b(a.z) | ((uint32_t)f2b(a.w) << 16);
        o.z = (uint32_t)f2b(b.x) | ((uint32_t)f2b(b.y) << 16);
        o.w = (uint32_t)f2b(b.z) | ((uint32_t)f2b(b.w) << 16);
        *(uint4*)&At[r * 136 + kc] = o;
    }
    __syncthreads();
    int wv = t >> 6, lane = t & 63;
    int m = lane & 15, qd = lane >> 4;
    floatx4 acc[8];
    #pragma unroll
    for (int c = 0; c < 8; c++) acc[c] = (floatx4){0.f, 0.f, 0.f, 0.f};
    const unsigned short* ap = &At[(wv * 16 + m) * 136 + qd * 8];
    const unsigned short* bp = &Bt[m * 136 + qd * 8];
    #pragma unroll
    for (int kk = 0; kk < 4; kk++) {
        short8 af = *(const short8*)(ap + kk * 32);
        #pragma unroll
        for (int c = 0; c < 8; c++) {
            short8 bf = *(const short8*)(bp + c * 16 * 136 + kk * 32);
            acc[c] = __builtin_amdgcn_mfma_f32_16x16x32_bf16(af, bf, acc[c], 0, 0, 0);
        }
    }
    #pragma unroll
    for (int reg = 0; reg < 4; reg++) {       // D[row=qd*4+reg][col=16c+m]
        int g = row0 + wv * 16 + qd * 4 + reg;
        if (g < N_NODES) {
            float di = rsqrtf((float)counts[g] + 1.0f);
            #pragma unroll
            for (int c = 0; c < 8; c++)
                h1s[g * 128 + c * 16 + m] = f2b(di * acc[c][reg]);
        }
    }
}

// ---------- 4. fused agg1 + GEMM2 ----------
// agg: r1[v] = relu(dv * (Σ h1s[N(v)] + h1s[v]) + b1) -> LDS A-tile (16 nodes/block)
// gemm: h2s[v] = dinv[v] * (r1 @ W2) via 1 MFMA col-tile per wave.
__global__ __launch_bounds__(256) void k_agg1g2(const unsigned short* __restrict__ h1s,
                                                const unsigned short* __restrict__ Wt2,
                                                const int* __restrict__ csr,
                                                const int* __restrict__ counts,
                                                const float* __restrict__ b1,
                                                unsigned short* __restrict__ h2s) {
    __shared__ unsigned short Bt[64 * 136];   // Wt2 [n=64][k=128] staged
    __shared__ unsigned short At[16 * 136];   // r1 tile [16 rows][128 k]
    int t = threadIdx.x;
    for (int i = t; i < 1024; i += 256) {     // stage Bt2
        int n = i >> 4, kc = (i & 15) * 8;
        *(uint4*)&Bt[n * 136 + kc] = *(const uint4*)(Wt2 + n * 128 + kc);
    }
    int wv = t >> 6, lane = t & 63;
    int q = lane >> 4, l = lane & 15;
    int v0 = blockIdx.x * 16;
    int v = v0 + wv * 4 + q;                  // 50000 = 3125*16: always valid
    int vv = (v < N_NODES) ? v : N_NODES - 1;
    int n = (v < N_NODES) ? counts[vv] : 0;
    float dv = rsqrtf((float)n + 1.0f);
    int n_eff = min(n, CAP);
    const int* cs = csr + vv * CAP;
    int nmax = n_eff;
    nmax = max(nmax, __shfl_xor(nmax, 16));
    nmax = max(nmax, __shfl_xor(nmax, 32));
    float a0, a1, a2, a3, a4, a5, a6, a7;
    {   // self-loop row (h1s prescaled by dinv)
        uint4 p = *(const uint4*)(h1s + vv * 128 + l * 8);
        a0 = bflo(p.x); a1 = bfhi(p.x); a2 = bflo(p.y); a3 = bfhi(p.y);
        a4 = bflo(p.z); a5 = bfhi(p.z); a6 = bflo(p.w); a7 = bfhi(p.w);
    }
    for (int base = 0; base < nmax; base += 16) {
        int idx = base + l;
        int e = (idx < n_eff) ? cs[idx] : 0;  // coalesced per quarter
        int mm = nmax - base; if (mm > 16) mm = 16;
        #pragma unroll 4
        for (int i = 0; i < mm; i++) {
            int s = __shfl(e, (q << 4) + i);
            if (base + i < n_eff) {           // uniform within quarter
                uint4 p = *(const uint4*)(h1s + s * 128 + l * 8);
                a0 += bflo(p.x); a1 += bfhi(p.x); a2 += bflo(p.y); a3 += bfhi(p.y);
                a4 += bflo(p.z); a5 += bfhi(p.z); a6 += bflo(p.w); a7 += bfhi(p.w);
            }
        }
    }
    {
        float4 bL = *(const float4*)(b1 + l * 8);
        float4 bH = *(const float4*)(b1 + l * 8 + 4);
        a0 = fmaxf(fmaf(dv, a0, bL.x), 0.f); a1 = fmaxf(fmaf(dv, a1, bL.y), 0.f);
        a2 = fmaxf(fmaf(dv, a2, bL.z), 0.f); a3 = fmaxf(fmaf(dv, a3, bL.w), 0.f);
        a4 = fmaxf(fmaf(dv, a4, bH.x), 0.f); a5 = fmaxf(fmaf(dv, a5, bH.y), 0.f);
        a6 = fmaxf(fmaf(dv, a6, bH.z), 0.f); a7 = fmaxf(fmaf(dv, a7, bH.w), 0.f);
        uint4 o;
        o.x = (uint32_t)f2b(a0) | ((uint32_t)f2b(a1) << 16);
        o.y = (uint32_t)f2b(a2) | ((uint32_t)f2b(a3) << 16);
        o.z = (uint32_t)f2b(a4) | ((uint32_t)f2b(a5) << 16);
        o.w = (uint32_t)f2b(a6) | ((uint32_t)f2b(a7) << 16);
        *(uint4*)&At[(wv * 4 + q) * 136 + l * 8] = o;   // r1 tile row
    }
    __syncthreads();
    // MFMA: wave wv -> col-tile wv (cols 16wv..16wv+15)
    int m = lane & 15, qd = lane >> 4;
    floatx4 acc = (floatx4){0.f, 0.f, 0.f, 0.f};
    const unsigned short* ap = &At[m * 136 + qd * 8];
    const unsigned short* bp = &Bt[(wv * 16 + m) * 136 + qd * 8];
    #pragma unroll
    for (int kk = 0; kk < 4; kk++) {
        short8 af = *(const short8*)(ap + kk * 32);
        short8 bf = *(const short8*)(bp + kk * 32);
        acc = __builtin_amdgcn_mfma_f32_16x16x32_bf16(af, bf, acc, 0, 0, 0);
    }
    #pragma unroll
    for (int reg = 0; reg < 4; reg++) {
        int g = v0 + qd * 4 + reg;
        if (g < N_NODES) {
            float dg = rsqrtf((float)counts[g] + 1.0f);   // prescale h2 rows
            h2s[g * 64 + wv * 16 + m] = f2b(dg * acc[reg]);
        }
    }
}

// ---------- 5. agg2 + head: h3 = relu(dv*Σ h2s + b2); out = log_softmax(h3@Wo+bo)
__global__ __launch_bounds__(256) void k_agg2(const unsigned short* __restrict__ h2s,
                                              const int* __restrict__ csr,
                                              const int* __restrict__ counts,
                                              const float* __restrict__ b2,
                                              const float* __restrict__ Wo,
                                              const float* __restrict__ bo,
                                              float* __restrict__ out) {
    int wave = (blockIdx.x * 256 + threadIdx.x) >> 6;
    int lane = threadIdx.x & 63;
    int q = lane >> 4, l = lane & 15;
    int v = wave * 4 + q;
    bool valid = v < N_NODES;
    int vv = valid ? v : N_NODES - 1;
    int n = valid ? counts[vv] : 0;
    float dv = rsqrtf((float)n + 1.0f);
    int n_eff = min(n, CAP);
    const int* cs = csr + vv * CAP;
    int nmax = n_eff;
    nmax = max(nmax, __shfl_xor(nmax, 16));
    nmax = max(nmax, __shfl_xor(nmax, 32));
    float a0, a1, a2, a3;
    {   // self-loop: h2s already prescaled by dinv
        uint2 p = *(const uint2*)(h2s + vv * 64 + l * 4);
        a0 = bflo(p.x); a1 = bfhi(p.x); a2 = bflo(p.y); a3 = bfhi(p.y);
    }
    for (int base = 0; base < nmax; base += 16) {
        int idx = base + l;
        int e = (idx < n_eff) ? cs[idx] : 0;
        int mm = nmax - base; if (mm > 16) mm = 16;
        #pragma unroll 4
        for (int i = 0; i < mm; i++) {
            int s = __shfl(e, (q << 4) + i);
            if (base + i < n_eff) {
                uint2 p = *(const uint2*)(h2s + s * 64 + l * 4);
                a0 += bflo(p.x); a1 += bfhi(p.x); a2 += bflo(p.y); a3 += bfhi(p.y);
            }
        }
    }
    float4 bb = *(const float4*)(b2 + l * 4);
    a0 = fmaxf(fmaf(dv, a0, bb.x), 0.f);
    a1 = fmaxf(fmaf(dv, a1, bb.y), 0.f);
    a2 = fmaxf(fmaf(dv, a2, bb.z), 0.f);
    a3 = fmaxf(fmaf(dv, a3, bb.w), 0.f);
    float4 w01 = *(const float4*)(Wo + l * 8);
    float4 w23 = *(const float4*)(Wo + l * 8 + 4);
    float l0 = a0 * w01.x + a1 * w01.z + a2 * w23.x + a3 * w23.z;
    float l1 = a0 * w01.y + a1 * w01.w + a2 * w23.y + a3 * w23.w;
    #pragma unroll
    for (int off = 8; off > 0; off >>= 1) {
        l0 += __shfl_xor(l0, off);
        l1 += __shfl_xor(l1, off);
    }
    if (l == 0 && valid) {
        float2 bof = *(const float2*)bo;
        l0 += bof.x; l1 += bof.y;
        float m = fmaxf(l0, l1);
        float ls = m + __logf(__expf(l0 - m) + __expf(l1 - m));
        *(float2*)(out + v * 2) = make_float2(l0 - ls, l1 - ls);
    }
}

extern "C" void kernel_launch(void* const* d_in, const int* in_sizes, int n_in,
                              void* d_out, int out_size, void* d_ws, size_t ws_size,
                              hipStream_t stream) {
    const float* x  = (const float*)d_in[0];
    const int* ei   = (const int*)d_in[1];
    const float* W1 = (const float*)d_in[2];
    const float* b1 = (const float*)d_in[3];
    const float* W2 = (const float*)d_in[4];
    const float* b2 = (const float*)d_in[5];
    const float* Wo = (const float*)d_in[6];
    const float* bo = (const float*)d_in[7];
    float* out      = (float*)d_out;
    const int* src = ei;             // edge_index[0]
    const int* dst = ei + N_EDGES;   // edge_index[1]

    char* w = (char*)d_ws;
    int* counts = (int*)(w + 0);                           // 200 KB (degrees)
    int* csr    = (int*)(w + 200704);                      // 16 MB  [node][CAP]
    unsigned short* Wt1 = (unsigned short*)(w + 16200704); // 32 KB  [n=128][k=128]
    unsigned short* Wt2 = (unsigned short*)(w + 16233472); // 16 KB  [n=64][k=128]
    unsigned short* h1s = (unsigned short*)(w + 16249856); // 12.8 MB (dinv-prescaled)
    unsigned short* h2s = (unsigned short*)(w + 29049856); // 6.4 MB  (dinv-prescaled)
    // total ws usage: ~35.4 MB

    k_prep  <<<292, 256, 0, stream>>>(W1, W2, Wt1, Wt2, counts);
    k_scat  <<<3125, 256, 0, stream>>>(src, dst, counts, csr);
    k_gemm1 <<<782, 256, 0, stream>>>(x, Wt1, counts, h1s);
    k_agg1g2<<<3125, 256, 0, stream>>>(h1s, Wt2, csr, counts, b1, h2s);
    k_agg2  <<<3125, 256, 0, stream>>>(h2s, csr, counts, b2, Wo, bo, out);
}

// Round 10
// 195.320 us; speedup vs baseline: 1.1331x; 1.0771x over previous
//
#include <hip/hip_runtime.h>
#include <stdint.h>

#define N_NODES 50000
#define N_EDGES 800000
#define CAP 80   // bucket capacity; deg ~ Poisson(16), P(deg>80) ~ 1e-25
// D_IN=128, H1=128, H2=64, C=2 — inputs fp32; intermediates bf16 (dinv-prescaled)

typedef __attribute__((ext_vector_type(8))) short short8;     // 8 bf16 (4 VGPRs)
typedef __attribute__((ext_vector_type(4))) float floatx4;    // MFMA acc

// ---------- bf16 helpers ----------
__device__ __forceinline__ float bflo(uint32_t u) { return __uint_as_float(u << 16); }
__device__ __forceinline__ float bfhi(uint32_t u) { return __uint_as_float(u & 0xffff0000u); }
__device__ __forceinline__ unsigned short f2b(float f) {
    uint32_t u = __float_as_uint(f);
    u += 0x7fffu + ((u >> 16) & 1u);   // RNE
    return (unsigned short)(u >> 16);
}

// ---------- 1. prep: zero counts, build Wt1/Wt2 bf16 transposes ----------
__global__ void k_prep(const float* __restrict__ W1, const float* __restrict__ W2,
                       unsigned short* __restrict__ Wt1, unsigned short* __restrict__ Wt2,
                       int* __restrict__ counts) {
    int gid = blockIdx.x * 256 + threadIdx.x;
    if (gid < 16384) {                     // Wt1[n][k] = bf16(W1[k][n])
        int k = gid >> 7, n = gid & 127;
        Wt1[n * 128 + k] = f2b(W1[gid]);
    } else if (gid < 24576) {              // Wt2[n][k] = bf16(W2[k][n])
        int j = gid - 16384;
        int k = j >> 6, n = j & 63;
        Wt2[n * 128 + k] = f2b(W2[j]);
    } else if (gid < 24576 + N_NODES) {
        counts[gid - 24576] = 0;
    }
}

// ---------- 2. one-pass CSR: count + bucket-append, 8 edges/thread (MLP=8) ----------
// Zero LDS. Two int4 loads each of src/dst (coalesced 16B/lane), 8 independent
// atomic chains in flight per thread.
__global__ __launch_bounds__(256) void k_scat(const int* __restrict__ src,
                                              const int* __restrict__ dst,
                                              int* __restrict__ counts,
                                              int* __restrict__ csr) {
    int i = blockIdx.x * 256 + threadIdx.x;   // edge-octet index
    if (i >= N_EDGES / 8) return;
    const int4* s4 = (const int4*)(src + i * 8);
    const int4* d4 = (const int4*)(dst + i * 8);
    int4 sa = s4[0], sb = s4[1];
    int4 da = d4[0], db = d4[1];
    int r0 = atomicAdd(&counts[da.x], 1);
    int r1 = atomicAdd(&counts[da.y], 1);
    int r2 = atomicAdd(&counts[da.z], 1);
    int r3 = atomicAdd(&counts[da.w], 1);
    int r4 = atomicAdd(&counts[db.x], 1);
    int r5 = atomicAdd(&counts[db.y], 1);
    int r6 = atomicAdd(&counts[db.z], 1);
    int r7 = atomicAdd(&counts[db.w], 1);
    if (r0 < CAP) csr[da.x * CAP + r0] = sa.x;
    if (r1 < CAP) csr[da.y * CAP + r1] = sa.y;
    if (r2 < CAP) csr[da.z * CAP + r2] = sa.z;
    if (r3 < CAP) csr[da.w * CAP + r3] = sa.w;
    if (r4 < CAP) csr[db.x * CAP + r4] = sb.x;
    if (r5 < CAP) csr[db.y * CAP + r5] = sb.y;
    if (r6 < CAP) csr[db.z * CAP + r6] = sb.z;
    if (r7 < CAP) csr[db.w * CAP + r7] = sb.w;
}

// ---------- 3. MFMA GEMM1: h1s[v] = dinv[v] * (bf16(x[v]) @ bf16(W1)) ----------
// 64 rows/block, full K=128 in LDS. dinv computed from counts (final after k_scat).
__global__ __launch_bounds__(256) void k_gemm1(const float* __restrict__ x,
                                               const unsigned short* __restrict__ Wt1,
                                               const int* __restrict__ counts,
                                               unsigned short* __restrict__ h1s) {
    __shared__ unsigned short At[64 * 136];   // 17.0 KB (pad 8 bf16)
    __shared__ unsigned short Bt[128 * 136];  // 34.0 KB
    int t = threadIdx.x;
    int row0 = blockIdx.x * 64;
    for (int i = t; i < 2048; i += 256) {     // stage Bt (Wt1 [n][k] bf16)
        int n = i >> 4, kc = (i & 15) * 8;
        *(uint4*)&Bt[n * 136 + kc] = *(const uint4*)(Wt1 + n * 128 + kc);
    }
    for (int i = t; i < 1024; i += 256) {     // stage At: fp32 -> bf16
        int r = i >> 4, kc = (i & 15) * 8;
        int g = row0 + r; if (g >= N_NODES) g = N_NODES - 1;
        const float* p = x + g * 128 + kc;
        float4 a = *(const float4*)p, b = *(const float4*)(p + 4);
        uint4 o;
        o.x = (uint32_t)f2b(a.x) | ((uint32_t)f2b(a.y) << 16);
        o.y = (uint32_t)f2b(a.z) | ((uint32_t)f2b(a.w) << 16);
        o.z = (uint32_t)f2b(b.x) | ((uint32_t)f2b(b.y) << 16);
        o.w = (uint32_t)f2b(b.z) | ((uint32_t)f2b(b.w) << 16);
        *(uint4*)&At[r * 136 + kc] = o;
    }
    __syncthreads();
    int wv = t >> 6, lane = t & 63;
    int m = lane & 15, qd = lane >> 4;
    floatx4 acc[8];
    #pragma unroll
    for (int c = 0; c < 8; c++) acc[c] = (floatx4){0.f, 0.f, 0.f, 0.f};
    const unsigned short* ap = &At[(wv * 16 + m) * 136 + qd * 8];
    const unsigned short* bp = &Bt[m * 136 + qd * 8];
    #pragma unroll
    for (int kk = 0; kk < 4; kk++) {
        short8 af = *(const short8*)(ap + kk * 32);
        #pragma unroll
        for (int c = 0; c < 8; c++) {
            short8 bf = *(const short8*)(bp + c * 16 * 136 + kk * 32);
            acc[c] = __builtin_amdgcn_mfma_f32_16x16x32_bf16(af, bf, acc[c], 0, 0, 0);
        }
    }
    #pragma unroll
    for (int reg = 0; reg < 4; reg++) {       // D[row=qd*4+reg][col=16c+m]
        int g = row0 + wv * 16 + qd * 4 + reg;
        if (g < N_NODES) {
            float di = rsqrtf((float)counts[g] + 1.0f);
            #pragma unroll
            for (int c = 0; c < 8; c++)
                h1s[g * 128 + c * 16 + m] = f2b(di * acc[c][reg]);
        }
    }
}

// ---------- 4. fused agg1 + GEMM2 ----------
// agg: r1[v] = relu(dv * (Σ h1s[N(v)] + h1s[v]) + b1) -> LDS A-tile (16 nodes/block)
// gemm: h2s[v] = dinv[v] * (r1 @ W2) via 1 MFMA col-tile per wave.
__global__ __launch_bounds__(256) void k_agg1g2(const unsigned short* __restrict__ h1s,
                                                const unsigned short* __restrict__ Wt2,
                                                const int* __restrict__ csr,
                                                const int* __restrict__ counts,
                                                const float* __restrict__ b1,
                                                unsigned short* __restrict__ h2s) {
    __shared__ unsigned short Bt[64 * 136];   // Wt2 [n=64][k=128] staged
    __shared__ unsigned short At[16 * 136];   // r1 tile [16 rows][128 k]
    int t = threadIdx.x;
    for (int i = t; i < 1024; i += 256) {     // stage Bt2
        int n = i >> 4, kc = (i & 15) * 8;
        *(uint4*)&Bt[n * 136 + kc] = *(const uint4*)(Wt2 + n * 128 + kc);
    }
    int wv = t >> 6, lane = t & 63;
    int q = lane >> 4, l = lane & 15;
    int v0 = blockIdx.x * 16;
    int v = v0 + wv * 4 + q;                  // 50000 = 3125*16: always valid
    int vv = (v < N_NODES) ? v : N_NODES - 1;
    int n = (v < N_NODES) ? counts[vv] : 0;
    float dv = rsqrtf((float)n + 1.0f);
    int n_eff = min(n, CAP);
    const int* cs = csr + vv * CAP;
    int nmax = n_eff;
    nmax = max(nmax, __shfl_xor(nmax, 16));
    nmax = max(nmax, __shfl_xor(nmax, 32));
    float a0, a1, a2, a3, a4, a5, a6, a7;
    {   // self-loop row (h1s prescaled by dinv)
        uint4 p = *(const uint4*)(h1s + vv * 128 + l * 8);
        a0 = bflo(p.x); a1 = bfhi(p.x); a2 = bflo(p.y); a3 = bfhi(p.y);
        a4 = bflo(p.z); a5 = bfhi(p.z); a6 = bflo(p.w); a7 = bfhi(p.w);
    }
    for (int base = 0; base < nmax; base += 16) {
        int idx = base + l;
        int e = (idx < n_eff) ? cs[idx] : 0;  // coalesced per quarter
        int mm = nmax - base; if (mm > 16) mm = 16;
        #pragma unroll 4
        for (int i = 0; i < mm; i++) {
            int s = __shfl(e, (q << 4) + i);
            if (base + i < n_eff) {           // uniform within quarter
                uint4 p = *(const uint4*)(h1s + s * 128 + l * 8);
                a0 += bflo(p.x); a1 += bfhi(p.x); a2 += bflo(p.y); a3 += bfhi(p.y);
                a4 += bflo(p.z); a5 += bfhi(p.z); a6 += bflo(p.w); a7 += bfhi(p.w);
            }
        }
    }
    {
        float4 bL = *(const float4*)(b1 + l * 8);
        float4 bH = *(const float4*)(b1 + l * 8 + 4);
        a0 = fmaxf(fmaf(dv, a0, bL.x), 0.f); a1 = fmaxf(fmaf(dv, a1, bL.y), 0.f);
        a2 = fmaxf(fmaf(dv, a2, bL.z), 0.f); a3 = fmaxf(fmaf(dv, a3, bL.w), 0.f);
        a4 = fmaxf(fmaf(dv, a4, bH.x), 0.f); a5 = fmaxf(fmaf(dv, a5, bH.y), 0.f);
        a6 = fmaxf(fmaf(dv, a6, bH.z), 0.f); a7 = fmaxf(fmaf(dv, a7, bH.w), 0.f);
        uint4 o;
        o.x = (uint32_t)f2b(a0) | ((uint32_t)f2b(a1) << 16);
        o.y = (uint32_t)f2b(a2) | ((uint32_t)f2b(a3) << 16);
        o.z = (uint32_t)f2b(a4) | ((uint32_t)f2b(a5) << 16);
        o.w = (uint32_t)f2b(a6) | ((uint32_t)f2b(a7) << 16);
        *(uint4*)&At[(wv * 4 + q) * 136 + l * 8] = o;   // r1 tile row
    }
    __syncthreads();
    // MFMA: wave wv -> col-tile wv (cols 16wv..16wv+15)
    int m = lane & 15, qd = lane >> 4;
    floatx4 acc = (floatx4){0.f, 0.f, 0.f, 0.f};
    const unsigned short* ap = &At[m * 136 + qd * 8];
    const unsigned short* bp = &Bt[(wv * 16 + m) * 136 + qd * 8];
    #pragma unroll
    for (int kk = 0; kk < 4; kk++) {
        short8 af = *(const short8*)(ap + kk * 32);
        short8 bf = *(const short8*)(bp + kk * 32);
        acc = __builtin_amdgcn_mfma_f32_16x16x32_bf16(af, bf, acc, 0, 0, 0);
    }
    #pragma unroll
    for (int reg = 0; reg < 4; reg++) {
        int g = v0 + qd * 4 + reg;
        if (g < N_NODES) {
            float dg = rsqrtf((float)counts[g] + 1.0f);   // prescale h2 rows
            h2s[g * 64 + wv * 16 + m] = f2b(dg * acc[reg]);
        }
    }
}

// ---------- 5. agg2 + head: h3 = relu(dv*Σ h2s + b2); out = log_softmax(h3@Wo+bo)
__global__ __launch_bounds__(256) void k_agg2(const unsigned short* __restrict__ h2s,
                                              const int* __restrict__ csr,
                                              const int* __restrict__ counts,
                                              const float* __restrict__ b2,
                                              const float* __restrict__ Wo,
                                              const float* __restrict__ bo,
                                              float* __restrict__ out) {
    int wave = (blockIdx.x * 256 + threadIdx.x) >> 6;
    int lane = threadIdx.x & 63;
    int q = lane >> 4, l = lane & 15;
    int v = wave * 4 + q;
    bool valid = v < N_NODES;
    int vv = valid ? v : N_NODES - 1;
    int n = valid ? counts[vv] : 0;
    float dv = rsqrtf((float)n + 1.0f);
    int n_eff = min(n, CAP);
    const int* cs = csr + vv * CAP;
    int nmax = n_eff;
    nmax = max(nmax, __shfl_xor(nmax, 16));
    nmax = max(nmax, __shfl_xor(nmax, 32));
    float a0, a1, a2, a3;
    {   // self-loop: h2s already prescaled by dinv
        uint2 p = *(const uint2*)(h2s + vv * 64 + l * 4);
        a0 = bflo(p.x); a1 = bfhi(p.x); a2 = bflo(p.y); a3 = bfhi(p.y);
    }
    for (int base = 0; base < nmax; base += 16) {
        int idx = base + l;
        int e = (idx < n_eff) ? cs[idx] : 0;
        int mm = nmax - base; if (mm > 16) mm = 16;
        #pragma unroll 4
        for (int i = 0; i < mm; i++) {
            int s = __shfl(e, (q << 4) + i);
            if (base + i < n_eff) {
                uint2 p = *(const uint2*)(h2s + s * 64 + l * 4);
                a0 += bflo(p.x); a1 += bfhi(p.x); a2 += bflo(p.y); a3 += bfhi(p.y);
            }
        }
    }
    float4 bb = *(const float4*)(b2 + l * 4);
    a0 = fmaxf(fmaf(dv, a0, bb.x), 0.f);
    a1 = fmaxf(fmaf(dv, a1, bb.y), 0.f);
    a2 = fmaxf(fmaf(dv, a2, bb.z), 0.f);
    a3 = fmaxf(fmaf(dv, a3, bb.w), 0.f);
    float4 w01 = *(const float4*)(Wo + l * 8);
    float4 w23 = *(const float4*)(Wo + l * 8 + 4);
    float l0 = a0 * w01.x + a1 * w01.z + a2 * w23.x + a3 * w23.z;
    float l1 = a0 * w01.y + a1 * w01.w + a2 * w23.y + a3 * w23.w;
    #pragma unroll
    for (int off = 8; off > 0; off >>= 1) {
        l0 += __shfl_xor(l0, off);
        l1 += __shfl_xor(l1, off);
    }
    if (l == 0 && valid) {
        float2 bof = *(const float2*)bo;
        l0 += bof.x; l1 += bof.y;
        float m = fmaxf(l0, l1);
        float ls = m + __logf(__expf(l0 - m) + __expf(l1 - m));
        *(float2*)(out + v * 2) = make_float2(l0 - ls, l1 - ls);
    }
}

extern "C" void kernel_launch(void* const* d_in, const int* in_sizes, int n_in,
                              void* d_out, int out_size, void* d_ws, size_t ws_size,
                              hipStream_t stream) {
    const float* x  = (const float*)d_in[0];
    const int* ei   = (const int*)d_in[1];
    const float* W1 = (const float*)d_in[2];
    const float* b1 = (const float*)d_in[3];
    const float* W2 = (const float*)d_in[4];
    const float* b2 = (const float*)d_in[5];
    const float* Wo = (const float*)d_in[6];
    const float* bo = (const float*)d_in[7];
    float* out      = (float*)d_out;
    const int* src = ei;             // edge_index[0]
    const int* dst = ei + N_EDGES;   // edge_index[1]

    char* w = (char*)d_ws;
    int* counts = (int*)(w + 0);                           // 200 KB (degrees)
    int* csr    = (int*)(w + 200704);                      // 16 MB  [node][CAP]
    unsigned short* Wt1 = (unsigned short*)(w + 16200704); // 32 KB  [n=128][k=128]
    unsigned short* Wt2 = (unsigned short*)(w + 16233472); // 16 KB  [n=64][k=128]
    unsigned short* h1s = (unsigned short*)(w + 16249856); // 12.8 MB (dinv-prescaled)
    unsigned short* h2s = (unsigned short*)(w + 29049856); // 6.4 MB  (dinv-prescaled)
    // total ws usage: ~35.4 MB

    k_prep  <<<292, 256, 0, stream>>>(W1, W2, Wt1, Wt2, counts);
    k_scat  <<<391, 256, 0, stream>>>(src, dst, counts, csr);   // 8 edges/thread
    k_gemm1 <<<782, 256, 0, stream>>>(x, Wt1, counts, h1s);
    k_agg1g2<<<3125, 256, 0, stream>>>(h1s, Wt2, csr, counts, b1, h2s);
    k_agg2  <<<3125, 256, 0, stream>>>(h2s, csr, counts, b2, Wo, bo, out);
}

// Round 11
// 192.917 us; speedup vs baseline: 1.1473x; 1.0125x over previous
//
#include <hip/hip_runtime.h>
#include <stdint.h>

#define N_NODES 50000
#define N_EDGES 800000
#define CAP 80        // bucket capacity; deg ~ Poisson(16), P(deg>80) ~ 1e-25
#define ZROW N_NODES  // zero-row index used to pad gather loops (rows 50000..50047 zeroed)
// D_IN=128, H1=128, H2=64, C=2 — inputs fp32; intermediates bf16 (dinv-prescaled)

typedef __attribute__((ext_vector_type(8))) short short8;     // 8 bf16 (4 VGPRs)
typedef __attribute__((ext_vector_type(4))) float floatx4;    // MFMA acc

// ---------- bf16 helpers ----------
__device__ __forceinline__ float bflo(uint32_t u) { return __uint_as_float(u << 16); }
__device__ __forceinline__ float bfhi(uint32_t u) { return __uint_as_float(u & 0xffff0000u); }
__device__ __forceinline__ unsigned short f2b(float f) {
    uint32_t u = __float_as_uint(f);
    u += 0x7fffu + ((u >> 16) & 1u);   // RNE
    return (unsigned short)(u >> 16);
}

// ---------- 1. prep: zero counts, build Wt1/Wt2 bf16 transposes ----------
__global__ void k_prep(const float* __restrict__ W1, const float* __restrict__ W2,
                       unsigned short* __restrict__ Wt1, unsigned short* __restrict__ Wt2,
                       int* __restrict__ counts) {
    int gid = blockIdx.x * 256 + threadIdx.x;
    if (gid < 16384) {                     // Wt1[n][k] = bf16(W1[k][n])
        int k = gid >> 7, n = gid & 127;
        Wt1[n * 128 + k] = f2b(W1[gid]);
    } else if (gid < 24576) {              // Wt2[n][k] = bf16(W2[k][n])
        int j = gid - 16384;
        int k = j >> 6, n = j & 63;
        Wt2[n * 128 + k] = f2b(W2[j]);
    } else if (gid < 24576 + N_NODES) {
        counts[gid - 24576] = 0;
    }
}

// ---------- 2. one-pass CSR: count + bucket-append, 8 edges/thread ----------
// Zero LDS, no range checks (randint guarantees [0, N_NODES)).
__global__ __launch_bounds__(256) void k_scat(const int* __restrict__ src,
                                              const int* __restrict__ dst,
                                              int* __restrict__ counts,
                                              int* __restrict__ csr) {
    int i = blockIdx.x * 256 + threadIdx.x;   // edge-octet index
    if (i >= N_EDGES / 8) return;
    const int4* s4 = (const int4*)(src + i * 8);
    const int4* d4 = (const int4*)(dst + i * 8);
    int4 sa = s4[0], sb = s4[1];
    int4 da = d4[0], db = d4[1];
    int r0 = atomicAdd(&counts[da.x], 1);
    int r1 = atomicAdd(&counts[da.y], 1);
    int r2 = atomicAdd(&counts[da.z], 1);
    int r3 = atomicAdd(&counts[da.w], 1);
    int r4 = atomicAdd(&counts[db.x], 1);
    int r5 = atomicAdd(&counts[db.y], 1);
    int r6 = atomicAdd(&counts[db.z], 1);
    int r7 = atomicAdd(&counts[db.w], 1);
    if (r0 < CAP) csr[da.x * CAP + r0] = sa.x;
    if (r1 < CAP) csr[da.y * CAP + r1] = sa.y;
    if (r2 < CAP) csr[da.z * CAP + r2] = sa.z;
    if (r3 < CAP) csr[da.w * CAP + r3] = sa.w;
    if (r4 < CAP) csr[db.x * CAP + r4] = sb.x;
    if (r5 < CAP) csr[db.y * CAP + r5] = sb.y;
    if (r6 < CAP) csr[db.z * CAP + r6] = sb.z;
    if (r7 < CAP) csr[db.w * CAP + r7] = sb.w;
}

// ---------- 3. MFMA GEMM1: h1s[v] = dinv[v] * (bf16(x[v]) @ bf16(W1)) ----------
// 64 rows/block, full K=128 in LDS. Rows >= N_NODES written as ZEROS (pad rows for
// branchless agg gathers); also zeroes the h2s pad rows.
__global__ __launch_bounds__(256) void k_gemm1(const float* __restrict__ x,
                                               const unsigned short* __restrict__ Wt1,
                                               const int* __restrict__ counts,
                                               unsigned short* __restrict__ h1s,
                                               unsigned short* __restrict__ h2s) {
    __shared__ unsigned short At[64 * 136];   // 17.0 KB (pad 8 bf16)
    __shared__ unsigned short Bt[128 * 136];  // 34.0 KB
    int t = threadIdx.x;
    int row0 = blockIdx.x * 64;
    for (int i = t; i < 2048; i += 256) {     // stage Bt (Wt1 [n][k] bf16)
        int n = i >> 4, kc = (i & 15) * 8;
        *(uint4*)&Bt[n * 136 + kc] = *(const uint4*)(Wt1 + n * 128 + kc);
    }
    for (int i = t; i < 1024; i += 256) {     // stage At: fp32 -> bf16
        int r = i >> 4, kc = (i & 15) * 8;
        int g = row0 + r; if (g >= N_NODES) g = N_NODES - 1;
        const float* p = x + g * 128 + kc;
        float4 a = *(const float4*)p, b = *(const float4*)(p + 4);
        uint4 o;
        o.x = (uint32_t)f2b(a.x) | ((uint32_t)f2b(a.y) << 16);
        o.y = (uint32_t)f2b(a.z) | ((uint32_t)f2b(a.w) << 16);
        o.z = (uint32_t)f2b(b.x) | ((uint32_t)f2b(b.y) << 16);
        o.w = (uint32_t)f2b(b.z) | ((uint32_t)f2b(b.w) << 16);
        *(uint4*)&At[r * 136 + kc] = o;
    }
    __syncthreads();
    int wv = t >> 6, lane = t & 63;
    int m = lane & 15, qd = lane >> 4;
    floatx4 acc[8];
    #pragma unroll
    for (int c = 0; c < 8; c++) acc[c] = (floatx4){0.f, 0.f, 0.f, 0.f};
    const unsigned short* ap = &At[(wv * 16 + m) * 136 + qd * 8];
    const unsigned short* bp = &Bt[m * 136 + qd * 8];
    #pragma unroll
    for (int kk = 0; kk < 4; kk++) {
        short8 af = *(const short8*)(ap + kk * 32);
        #pragma unroll
        for (int c = 0; c < 8; c++) {
            short8 bf = *(const short8*)(bp + c * 16 * 136 + kk * 32);
            acc[c] = __builtin_amdgcn_mfma_f32_16x16x32_bf16(af, bf, acc[c], 0, 0, 0);
        }
    }
    #pragma unroll
    for (int reg = 0; reg < 4; reg++) {       // D[row=qd*4+reg][col=16c+m]
        int g = row0 + wv * 16 + qd * 4 + reg;
        if (g < N_NODES) {
            float di = rsqrtf((float)counts[g] + 1.0f);
            #pragma unroll
            for (int c = 0; c < 8; c++)
                h1s[g * 128 + c * 16 + m] = f2b(di * acc[c][reg]);
        } else {                              // zero pad rows (branchless-agg target)
            #pragma unroll
            for (int c = 0; c < 8; c++)
                h1s[g * 128 + c * 16 + m] = 0;
            #pragma unroll
            for (int c = 0; c < 4; c++)
                h2s[g * 64 + c * 16 + m] = 0;
        }
    }
}

// ---------- 4. fused agg1 + GEMM2 ----------
// agg: r1[v] = relu(dv * (Σ h1s[N(v)] + h1s[v]) + b1) -> LDS A-tile (16 nodes/block)
// Branchless gather: pad slots point at zero row ZROW. Then 1 MFMA col-tile/wave.
__global__ __launch_bounds__(256) void k_agg1g2(const unsigned short* __restrict__ h1s,
                                                const unsigned short* __restrict__ Wt2,
                                                const int* __restrict__ csr,
                                                const int* __restrict__ counts,
                                                const float* __restrict__ b1,
                                                unsigned short* __restrict__ h2s) {
    __shared__ unsigned short Bt[64 * 136];   // Wt2 [n=64][k=128] staged
    __shared__ unsigned short At[16 * 136];   // r1 tile [16 rows][128 k]
    int t = threadIdx.x;
    for (int i = t; i < 1024; i += 256) {     // stage Bt2
        int n = i >> 4, kc = (i & 15) * 8;
        *(uint4*)&Bt[n * 136 + kc] = *(const uint4*)(Wt2 + n * 128 + kc);
    }
    int wv = t >> 6, lane = t & 63;
    int q = lane >> 4, l = lane & 15;
    int v0 = blockIdx.x * 16;
    int v = v0 + wv * 4 + q;                  // 50000 = 3125*16: always valid
    int n = counts[v];
    float dv = rsqrtf((float)n + 1.0f);
    int n_eff = min(n, CAP);
    const int* cs = csr + v * CAP;
    int nmax = n_eff;
    nmax = max(nmax, __shfl_xor(nmax, 16));
    nmax = max(nmax, __shfl_xor(nmax, 32));
    float a0, a1, a2, a3, a4, a5, a6, a7;
    {   // self-loop row (h1s prescaled by dinv)
        uint4 p = *(const uint4*)(h1s + v * 128 + l * 8);
        a0 = bflo(p.x); a1 = bfhi(p.x); a2 = bflo(p.y); a3 = bfhi(p.y);
        a4 = bflo(p.z); a5 = bfhi(p.z); a6 = bflo(p.w); a7 = bfhi(p.w);
    }
    for (int base = 0; base < nmax; base += 16) {
        int idx = base + l;
        int e = (idx < n_eff) ? cs[idx] : ZROW;   // pad -> zero row
        int mm = nmax - base; if (mm > 16) mm = 16;
        #pragma unroll 4
        for (int i = 0; i < mm; i++) {
            int s = __shfl(e, (q << 4) + i);      // ZROW contributes exact 0.0f
            uint4 p = *(const uint4*)(h1s + s * 128 + l * 8);
            a0 += bflo(p.x); a1 += bfhi(p.x); a2 += bflo(p.y); a3 += bfhi(p.y);
            a4 += bflo(p.z); a5 += bfhi(p.z); a6 += bflo(p.w); a7 += bfhi(p.w);
        }
    }
    {
        float4 bL = *(const float4*)(b1 + l * 8);
        float4 bH = *(const float4*)(b1 + l * 8 + 4);
        a0 = fmaxf(fmaf(dv, a0, bL.x), 0.f); a1 = fmaxf(fmaf(dv, a1, bL.y), 0.f);
        a2 = fmaxf(fmaf(dv, a2, bL.z), 0.f); a3 = fmaxf(fmaf(dv, a3, bL.w), 0.f);
        a4 = fmaxf(fmaf(dv, a4, bH.x), 0.f); a5 = fmaxf(fmaf(dv, a5, bH.y), 0.f);
        a6 = fmaxf(fmaf(dv, a6, bH.z), 0.f); a7 = fmaxf(fmaf(dv, a7, bH.w), 0.f);
        uint4 o;
        o.x = (uint32_t)f2b(a0) | ((uint32_t)f2b(a1) << 16);
        o.y = (uint32_t)f2b(a2) | ((uint32_t)f2b(a3) << 16);
        o.z = (uint32_t)f2b(a4) | ((uint32_t)f2b(a5) << 16);
        o.w = (uint32_t)f2b(a6) | ((uint32_t)f2b(a7) << 16);
        *(uint4*)&At[(wv * 4 + q) * 136 + l * 8] = o;   // r1 tile row
    }
    __syncthreads();
    // MFMA: wave wv -> col-tile wv (cols 16wv..16wv+15)
    int m = lane & 15, qd = lane >> 4;
    floatx4 acc = (floatx4){0.f, 0.f, 0.f, 0.f};
    const unsigned short* ap = &At[m * 136 + qd * 8];
    const unsigned short* bp = &Bt[(wv * 16 + m) * 136 + qd * 8];
    #pragma unroll
    for (int kk = 0; kk < 4; kk++) {
        short8 af = *(const short8*)(ap + kk * 32);
        short8 bf = *(const short8*)(bp + kk * 32);
        acc = __builtin_amdgcn_mfma_f32_16x16x32_bf16(af, bf, acc, 0, 0, 0);
    }
    #pragma unroll
    for (int reg = 0; reg < 4; reg++) {
        int g = v0 + qd * 4 + reg;
        float dg = rsqrtf((float)counts[g] + 1.0f);   // prescale h2 rows
        h2s[g * 64 + wv * 16 + m] = f2b(dg * acc[reg]);
    }
}

// ---------- 5. agg2 + head: h3 = relu(dv*Σ h2s + b2); out = log_softmax(h3@Wo+bo)
__global__ __launch_bounds__(256) void k_agg2(const unsigned short* __restrict__ h2s,
                                              const int* __restrict__ csr,
                                              const int* __restrict__ counts,
                                              const float* __restrict__ b2,
                                              const float* __restrict__ Wo,
                                              const float* __restrict__ bo,
                                              float* __restrict__ out) {
    int wave = (blockIdx.x * 256 + threadIdx.x) >> 6;
    int lane = threadIdx.x & 63;
    int q = lane >> 4, l = lane & 15;
    int v = wave * 4 + q;                     // 3125*4*4 = 50000: always valid
    int n = counts[v];
    float dv = rsqrtf((float)n + 1.0f);
    int n_eff = min(n, CAP);
    const int* cs = csr + v * CAP;
    int nmax = n_eff;
    nmax = max(nmax, __shfl_xor(nmax, 16));
    nmax = max(nmax, __shfl_xor(nmax, 32));
    float a0, a1, a2, a3;
    {   // self-loop: h2s already prescaled by dinv
        uint2 p = *(const uint2*)(h2s + v * 64 + l * 4);
        a0 = bflo(p.x); a1 = bfhi(p.x); a2 = bflo(p.y); a3 = bfhi(p.y);
    }
    for (int base = 0; base < nmax; base += 16) {
        int idx = base + l;
        int e = (idx < n_eff) ? cs[idx] : ZROW;   // pad -> zero row
        int mm = nmax - base; if (mm > 16) mm = 16;
        #pragma unroll 4
        for (int i = 0; i < mm; i++) {
            int s = __shfl(e, (q << 4) + i);
            uint2 p = *(const uint2*)(h2s + s * 64 + l * 4);
            a0 += bflo(p.x); a1 += bfhi(p.x); a2 += bflo(p.y); a3 += bfhi(p.y);
        }
    }
    float4 bb = *(const float4*)(b2 + l * 4);
    a0 = fmaxf(fmaf(dv, a0, bb.x), 0.f);
    a1 = fmaxf(fmaf(dv, a1, bb.y), 0.f);
    a2 = fmaxf(fmaf(dv, a2, bb.z), 0.f);
    a3 = fmaxf(fmaf(dv, a3, bb.w), 0.f);
    float4 w01 = *(const float4*)(Wo + l * 8);
    float4 w23 = *(const float4*)(Wo + l * 8 + 4);
    float l0 = a0 * w01.x + a1 * w01.z + a2 * w23.x + a3 * w23.z;
    float l1 = a0 * w01.y + a1 * w01.w + a2 * w23.y + a3 * w23.w;
    #pragma unroll
    for (int off = 8; off > 0; off >>= 1) {
        l0 += __shfl_xor(l0, off);
        l1 += __shfl_xor(l1, off);
    }
    if (l == 0) {
        float2 bof = *(const float2*)bo;
        l0 += bof.x; l1 += bof.y;
        float m = fmaxf(l0, l1);
        float ls = m + __logf(__expf(l0 - m) + __expf(l1 - m));
        *(float2*)(out + v * 2) = make_float2(l0 - ls, l1 - ls);
    }
}

extern "C" void kernel_launch(void* const* d_in, const int* in_sizes, int n_in,
                              void* d_out, int out_size, void* d_ws, size_t ws_size,
                              hipStream_t stream) {
    const float* x  = (const float*)d_in[0];
    const int* ei   = (const int*)d_in[1];
    const float* W1 = (const float*)d_in[2];
    const float* b1 = (const float*)d_in[3];
    const float* W2 = (const float*)d_in[4];
    const float* b2 = (const float*)d_in[5];
    const float* Wo = (const float*)d_in[6];
    const float* bo = (const float*)d_in[7];
    float* out      = (float*)d_out;
    const int* src = ei;             // edge_index[0]
    const int* dst = ei + N_EDGES;   // edge_index[1]

    char* w = (char*)d_ws;
    int* counts = (int*)(w + 0);                           // 200 KB (degrees)
    int* csr    = (int*)(w + 200704);                      // 16 MB  [node][CAP]
    unsigned short* Wt1 = (unsigned short*)(w + 16200704); // 32 KB  [n=128][k=128]
    unsigned short* Wt2 = (unsigned short*)(w + 16233472); // 16 KB  [n=64][k=128]
    unsigned short* h1s = (unsigned short*)(w + 16249856); // 12.81 MB (50048 rows, pad zeroed)
    unsigned short* h2s = (unsigned short*)(w + 29062144); // 6.41 MB  (50048 rows, pad zeroed)
    // total ws usage: ~35.5 MB

    k_prep  <<<292, 256, 0, stream>>>(W1, W2, Wt1, Wt2, counts);
    k_scat  <<<391, 256, 0, stream>>>(src, dst, counts, csr);   // 8 edges/thread
    k_gemm1 <<<782, 256, 0, stream>>>(x, Wt1, counts, h1s, h2s);
    k_agg1g2<<<3125, 256, 0, stream>>>(h1s, Wt2, csr, counts, b1, h2s);
    k_agg2  <<<3125, 256, 0, stream>>>(h2s, csr, counts, b2, Wo, bo, out);
}